// Round 9
// baseline (183.795 us; speedup 1.0000x reference)
//
#include <hip/hip_runtime.h>

typedef float  f32x4  __attribute__((ext_vector_type(4)));
typedef short  short8 __attribute__((ext_vector_type(8)));
typedef __bf16 bf16x8 __attribute__((ext_vector_type(8)));

#define DEV static __device__ __forceinline__
#define SB  __builtin_amdgcn_sched_barrier(0)

DEV f32x4 mfma16(short8 a, short8 b, f32x4 c) {
  return __builtin_amdgcn_mfma_f32_16x16x32_bf16(
      __builtin_bit_cast(bf16x8, a), __builtin_bit_cast(bf16x8, b), c, 0, 0, 0);
}

// split f32 into bf16 hi (truncated) + bf16 lo (RNE of residual)
DEV void splitf(float f, unsigned short& hi, unsigned short& lo) {
  unsigned u = __builtin_bit_cast(unsigned, f);
  hi = (unsigned short)(u >> 16);
  float hf = __builtin_bit_cast(float, u & 0xFFFF0000u);
  float r = f - hf;
  unsigned v = __builtin_bit_cast(unsigned, r);
  lo = (unsigned short)((v + 0x7FFFu + ((v >> 16) & 1u)) >> 16);
}

#define DDIM 640
#define KCH  20                    // 640 / 32 k-chunks total (10 per wave)
#define MKP_ELEMS (KCH*2*4*64*8)   // 81920 ushorts = 160KB
#define MVP_OFF   MKP_ELEMS

// Pack Mk / Mv^T in MFMA fragment order as bf16 hi/lo (see R1 comments).
// MkP: [c(20)][plane(2)][g(4)][lane(64)][j(8)] holds Mk[m=16g+(l&15)][d=32c+8*(l>>4)+j]
// MvP: [n(40)][c(2)][plane(2)][lane(64)][j(8)] holds Mv[m=32c+8*(l>>4)+j][d=16n+(l&15)]
__global__ void ea_pack(const float* __restrict__ Mk, const float* __restrict__ Mv,
                        unsigned short* __restrict__ ws) {
  int tid = blockIdx.x * 256 + threadIdx.x;
  unsigned short* MkP = ws;
  unsigned short* MvP = ws + MVP_OFF;
  if (tid < 5120) {
    int c = tid >> 8;
    int g = (tid >> 6) & 3;
    int l = tid & 63;
    int t = l & 15, q = l >> 4;
    const float* src = Mk + (16*g + t) * DDIM + 32*c + 8*q;
    unsigned short* dh = MkP + (((c*2 + 0)*4 + g)*64 + l)*8;
    unsigned short* dl = MkP + (((c*2 + 1)*4 + g)*64 + l)*8;
#pragma unroll
    for (int j = 0; j < 8; ++j) splitf(src[j], dh[j], dl[j]);
  } else if (tid < 10240) {
    int s = tid - 5120;
    int n = s >> 7;
    int c = (s >> 6) & 1;
    int l = s & 63;
    int t = l & 15, q = l >> 4;
    const float* src = Mv + (32*c + 8*q) * DDIM + 16*n + t;
    unsigned short* dh = MvP + (((n*2 + c)*2 + 0)*64 + l)*8;
    unsigned short* dl = MvP + (((n*2 + c)*2 + 1)*64 + l)*8;
#pragma unroll
    for (int j = 0; j < 8; ++j) splitf(src[j*DDIM], dh[j], dl[j]);
  }
}

#define LOADX(X0, X1, i) { X0 = *(const f32x4*)(xp + 32*(i)); \
                           X1 = *(const f32x4*)(xp + 32*(i) + 4); }

#define SPLITX(X0, X1)                                                       \
  splitf(X0[0], ah.u[0], al.u[0]); splitf(X0[1], ah.u[1], al.u[1]);          \
  splitf(X0[2], ah.u[2], al.u[2]); splitf(X0[3], ah.u[3], al.u[3]);          \
  splitf(X1[0], ah.u[4], al.u[4]); splitf(X1[1], ah.u[5], al.u[5]);          \
  splitf(X1[2], ah.u[6], al.u[6]); splitf(X1[3], ah.u[7], al.u[7]);

#define MFMAS()                                                              \
  acc[0] = mfma16(ah.s, fh0, acc[0]); acc[1] = mfma16(ah.s, fh1, acc[1]);    \
  acc[2] = mfma16(ah.s, fh2, acc[2]); acc[3] = mfma16(ah.s, fh3, acc[3]);    \
  acc[0] = mfma16(al.s, fh0, acc[0]); acc[1] = mfma16(al.s, fh1, acc[1]);    \
  acc[2] = mfma16(al.s, fh2, acc[2]); acc[3] = mfma16(al.s, fh3, acc[3]);    \
  acc[0] = mfma16(ah.s, fl0, acc[0]); acc[1] = mfma16(ah.s, fl1, acc[1]);    \
  acc[2] = mfma16(ah.s, fl2, acc[2]); acc[3] = mfma16(ah.s, fl3, acc[3]);

// One G1 step (local chunk i of this wave's 10): issue 8 frag loads (L2),
// consume x pair (SPLITX), THEN reload the freed regs for chunk i+2
// (consume-then-reload, R6's proven order), then 12 MFMA.
#define G1_IT(i, X0, X1) {                                                   \
  SB;                                                                        \
  { const unsigned short* s_ = mkb + (i)*4096 + l*8;                         \
    fh0 = *(const short8*)(s_);        fh1 = *(const short8*)(s_ + 512);     \
    fh2 = *(const short8*)(s_ + 1024); fh3 = *(const short8*)(s_ + 1536);    \
    fl0 = *(const short8*)(s_ + 2048); fl1 = *(const short8*)(s_ + 2560);    \
    fl2 = *(const short8*)(s_ + 3072); fl3 = *(const short8*)(s_ + 3584);    \
    SB;                                                                      \
    SPLITX(X0, X1)                                                           \
    SB;                                                                      \
    if ((i) + 2 < 10) { LOADX(X0, X1, (i)+2) }                               \
    SB;                                                                      \
    MFMAS() }                                                                \
  SB;                                                                        \
}

// Split-D: 16 rows per 128-thread block; wave h computes partial scores over
// d in [320h, 320h+320) (10 k-chunks), partials summed via LDS, softmax split
// 8 rows/wave, GEMM2 split by n (wave h does n in [20h, 20h+20)). Only two
// __syncthreads per block. Grid 4096 -> up to 24 waves/CU (vs 16 cap before).
__global__ __launch_bounds__(128, 6) void ea_main(const float* __restrict__ x,
                                                  const unsigned short* __restrict__ MkP,
                                                  const unsigned short* __restrict__ MvP,
                                                  float* __restrict__ out) {
  __shared__ float Pld[2][16][68];                         // 8.5KB partial scores
  __shared__ __align__(16) unsigned short Wh[16][64];      // 2KB
  __shared__ __align__(16) unsigned short Wl[16][64];      // 2KB
  const int tid = threadIdx.x;
  const int h = tid >> 6;           // wave: 0 or 1
  const int l = tid & 63;
  const int t = l & 15;
  const int q = l >> 4;
  const long row0 = (long)blockIdx.x * 16;

  // ---------------- GEMM1: partial scores over this wave's d-half ----------------
  const float* xp = x + (row0 + t) * DDIM + 320*h + 8*q;
  const unsigned short* mkb = MkP + (10*h) * 4096;
  f32x4 acc[4];
#pragma unroll
  for (int g = 0; g < 4; ++g) acc[g] = (f32x4){0.f, 0.f, 0.f, 0.f};

  f32x4 xA0, xA1, xB0, xB1;
  short8 fh0,fh1,fh2,fh3, fl0,fl1,fl2,fl3;
  union { short8 s; unsigned short u[8]; } ah, al;

  LOADX(xA0,xA1, 0) LOADX(xB0,xB1, 1)
  G1_IT(0, xA0,xA1) G1_IT(1, xB0,xB1)
  G1_IT(2, xA0,xA1) G1_IT(3, xB0,xB1)
  G1_IT(4, xA0,xA1) G1_IT(5, xB0,xB1)
  G1_IT(6, xA0,xA1) G1_IT(7, xB0,xB1)
  G1_IT(8, xA0,xA1) G1_IT(9, xB0,xB1)

  // scatter partial scores: lane holds S_h[row=4q+j][m=16g+t]
#pragma unroll
  for (int g = 0; g < 4; ++g)
#pragma unroll
    for (int j = 0; j < 4; ++j)
      Pld[h][4*q + j][16*g + t] = acc[g][j];
  __syncthreads();

  // ---------------- softmax: 8 rows per wave, 8 lanes per row ----------------
  {
    const int R = 8*h + (l >> 3);    // this lane's row
    const int s = l & 7;             // m-granule within row
    f32x4 a0 = *(const f32x4*)&Pld[0][R][8*s];
    f32x4 a1 = *(const f32x4*)&Pld[0][R][8*s + 4];
    f32x4 b0 = *(const f32x4*)&Pld[1][R][8*s];
    f32x4 b1 = *(const f32x4*)&Pld[1][R][8*s + 4];
    f32x4 v0 = a0 + b0, v1 = a1 + b1;
    float mx = fmaxf(fmaxf(fmaxf(v0[0], v0[1]), fmaxf(v0[2], v0[3])),
                     fmaxf(fmaxf(v1[0], v1[1]), fmaxf(v1[2], v1[3])));
#pragma unroll
    for (int mk = 1; mk <= 4; mk <<= 1) mx = fmaxf(mx, __shfl_xor(mx, mk, 64));
    float pv[8], sum = 0.f;
#pragma unroll
    for (int j = 0; j < 4; ++j) { pv[j]   = exp2f((v0[j] - mx) * 1.44269504f); sum += pv[j]; }
#pragma unroll
    for (int j = 0; j < 4; ++j) { pv[4+j] = exp2f((v1[j] - mx) * 1.44269504f); sum += pv[4+j]; }
#pragma unroll
    for (int mk = 1; mk <= 4; mk <<= 1) sum += __shfl_xor(sum, mk, 64);
    float inv = 1.0f / sum;
    union { short8 s8; unsigned short u[8]; } wh, wl;
#pragma unroll
    for (int j = 0; j < 8; ++j) splitf(pv[j] * inv, wh.u[j], wl.u[j]);
    const int gr = (s ^ (R & 7)) * 8;          // granule XOR swizzle (matches G2 read)
    *(short8*)&Wh[R][gr] = wh.s8;
    *(short8*)&Wl[R][gr] = wl.s8;
  }
  __syncthreads();

  // hoisted GEMM2 A-fragments: A[row=t][k=32c+8q+j]  (all 16 rows, both waves)
  short8 aH0, aH1, aL0, aL1;
  {
    const int sw  = (t & 7) << 3;
    const int ms0 = (8*q) ^ sw;
    const int ms1 = (32 + 8*q) ^ sw;
    aH0 = *(const short8*)&Wh[t][ms0];
    aH1 = *(const short8*)&Wh[t][ms1];
    aL0 = *(const short8*)&Wl[t][ms0];
    aL1 = *(const short8*)&Wl[t][ms1];
  }

  // ---------------- GEMM2: wave h does n in [20h, 20h+20), A/B dbuf ----------------
  const unsigned short* mvb = MvP + (20*h) * 2048;
  short8 vAh0, vAh1, vAl0, vAl1, vBh0, vBh1, vBl0, vBl1;
  {
    const unsigned short* mvp = mvb + l*8;     // local n = 0
    vAh0 = *(const short8*)(mvp);        vAl0 = *(const short8*)(mvp + 512);
    vAh1 = *(const short8*)(mvp + 1024); vAl1 = *(const short8*)(mvp + 1536);
  }
  float* opb = out + (row0 + 4*q) * DDIM + 320*h + t;

#pragma unroll 2
  for (int n = 0; n < 20; n += 2) {
    {   // prefetch B <- n+1
      const unsigned short* mvp = mvb + (n + 1) * 2048 + l*8;
      vBh0 = *(const short8*)(mvp);        vBl0 = *(const short8*)(mvp + 512);
      vBh1 = *(const short8*)(mvp + 1024); vBl1 = *(const short8*)(mvp + 1536);
    }
    {   // compute n with A
      f32x4 o = (f32x4){0.f,0.f,0.f,0.f};
      o = mfma16(aH0, vAh0, o); o = mfma16(aL0, vAh0, o); o = mfma16(aH0, vAl0, o);
      o = mfma16(aH1, vAh1, o); o = mfma16(aL1, vAh1, o); o = mfma16(aH1, vAl1, o);
      float* op = opb + 16*n;
#pragma unroll
      for (int j = 0; j < 4; ++j) op[j * DDIM] = o[j];
    }
    if (n + 2 < 20) {   // prefetch A <- n+2
      const unsigned short* mvp = mvb + (n + 2) * 2048 + l*8;
      vAh0 = *(const short8*)(mvp);        vAl0 = *(const short8*)(mvp + 512);
      vAh1 = *(const short8*)(mvp + 1024); vAl1 = *(const short8*)(mvp + 1536);
    }
    {   // compute n+1 with B
      f32x4 o = (f32x4){0.f,0.f,0.f,0.f};
      o = mfma16(aH0, vBh0, o); o = mfma16(aL0, vBh0, o); o = mfma16(aH0, vBl0, o);
      o = mfma16(aH1, vBh1, o); o = mfma16(aL1, vBh1, o); o = mfma16(aH1, vBl1, o);
      float* op = opb + 16*(n + 1);
#pragma unroll
      for (int j = 0; j < 4; ++j) op[j * DDIM] = o[j];
    }
  }
}

extern "C" void kernel_launch(void* const* d_in, const int* in_sizes, int n_in,
                              void* d_out, int out_size, void* d_ws, size_t ws_size,
                              hipStream_t stream) {
  const float* x  = (const float*)d_in[0];
  const float* Mk = (const float*)d_in[1];
  const float* Mv = (const float*)d_in[2];
  float* outp = (float*)d_out;
  unsigned short* ws = (unsigned short*)d_ws;

  ea_pack<<<40, 256, 0, stream>>>(Mk, Mv, ws);
  ea_main<<<4096, 128, 0, stream>>>(x, ws, ws + MVP_OFF, outp);
}

// Round 10
// 148.965 us; speedup vs baseline: 1.2338x; 1.2338x over previous
//
#include <hip/hip_runtime.h>

typedef float  f32x4  __attribute__((ext_vector_type(4)));
typedef short  short8 __attribute__((ext_vector_type(8)));
typedef __bf16 bf16x8 __attribute__((ext_vector_type(8)));

#define DEV static __device__ __forceinline__
#define SB  __builtin_amdgcn_sched_barrier(0)

DEV f32x4 mfma16(short8 a, short8 b, f32x4 c) {
  return __builtin_amdgcn_mfma_f32_16x16x32_bf16(
      __builtin_bit_cast(bf16x8, a), __builtin_bit_cast(bf16x8, b), c, 0, 0, 0);
}

// split f32 into bf16 hi (truncated) + bf16 lo (RNE of residual)
DEV void splitf(float f, unsigned short& hi, unsigned short& lo) {
  unsigned u = __builtin_bit_cast(unsigned, f);
  hi = (unsigned short)(u >> 16);
  float hf = __builtin_bit_cast(float, u & 0xFFFF0000u);
  float r = f - hf;
  unsigned v = __builtin_bit_cast(unsigned, r);
  lo = (unsigned short)((v + 0x7FFFu + ((v >> 16) & 1u)) >> 16);
}

#define DDIM 640
#define KCH  20                    // 640 / 32 k-chunks for GEMM1
#define MKP_ELEMS (KCH*2*4*64*8)   // 81920 ushorts = 160KB
#define MVP_OFF   MKP_ELEMS

// Pack Mk / Mv^T in MFMA fragment order as bf16 hi/lo.
// MkP: [c(20)][plane(2)][g(4)][lane(64)][j(8)] holds Mk[m=16g+(l&15)][d=32c+8*(l>>4)+j]
// MvP: [n(40)][c(2)][plane(2)][lane(64)][j(8)] holds Mv[m=32c+8*(l>>4)+j][d=16n+(l&15)]
__global__ void ea_pack(const float* __restrict__ Mk, const float* __restrict__ Mv,
                        unsigned short* __restrict__ ws) {
  int tid = blockIdx.x * 256 + threadIdx.x;
  unsigned short* MkP = ws;
  unsigned short* MvP = ws + MVP_OFF;
  if (tid < 5120) {
    int c = tid >> 8;
    int g = (tid >> 6) & 3;
    int l = tid & 63;
    int t = l & 15, q = l >> 4;
    const float* src = Mk + (16*g + t) * DDIM + 32*c + 8*q;
    unsigned short* dh = MkP + (((c*2 + 0)*4 + g)*64 + l)*8;
    unsigned short* dl = MkP + (((c*2 + 1)*4 + g)*64 + l)*8;
#pragma unroll
    for (int j = 0; j < 8; ++j) splitf(src[j], dh[j], dl[j]);
  } else if (tid < 10240) {
    int s = tid - 5120;
    int n = s >> 7;
    int c = (s >> 6) & 1;
    int l = s & 63;
    int t = l & 15, q = l >> 4;
    const float* src = Mv + (32*c + 8*q) * DDIM + 16*n + t;
    unsigned short* dh = MvP + (((n*2 + c)*2 + 0)*64 + l)*8;
    unsigned short* dl = MvP + (((n*2 + c)*2 + 1)*64 + l)*8;
#pragma unroll
    for (int j = 0; j < 8; ++j) splitf(src[j*DDIM], dh[j], dl[j]);
  }
}

#define LOADX(X0, X1, c) { X0 = *(const f32x4*)(xp + 32*(c)); \
                           X1 = *(const f32x4*)(xp + 32*(c) + 4); }

#define LOADFA(c) { const unsigned short* p_ = MkP + (c)*4096 + l8;          \
  fa0 = *(const short8*)(p_);        fa1 = *(const short8*)(p_ + 512);       \
  fa2 = *(const short8*)(p_ + 1024); fa3 = *(const short8*)(p_ + 1536);      \
  fa4 = *(const short8*)(p_ + 2048); fa5 = *(const short8*)(p_ + 2560);     \
  fa6 = *(const short8*)(p_ + 3072); fa7 = *(const short8*)(p_ + 3584); }

#define LOADFB(c) { const unsigned short* p_ = MkP + (c)*4096 + l8;          \
  fb0 = *(const short8*)(p_);        fb1 = *(const short8*)(p_ + 512);       \
  fb2 = *(const short8*)(p_ + 1024); fb3 = *(const short8*)(p_ + 1536);      \
  fb4 = *(const short8*)(p_ + 2048); fb5 = *(const short8*)(p_ + 2560);     \
  fb6 = *(const short8*)(p_ + 3072); fb7 = *(const short8*)(p_ + 3584); }

#define SPLITX(X0, X1)                                                       \
  splitf(X0[0], ah.u[0], al.u[0]); splitf(X0[1], ah.u[1], al.u[1]);          \
  splitf(X0[2], ah.u[2], al.u[2]); splitf(X0[3], ah.u[3], al.u[3]);          \
  splitf(X1[0], ah.u[4], al.u[4]); splitf(X1[1], ah.u[5], al.u[5]);          \
  splitf(X1[2], ah.u[6], al.u[6]); splitf(X1[3], ah.u[7], al.u[7]);

#define MFMAS_A()                                                            \
  acc[0] = mfma16(ah.s, fa0, acc[0]); acc[1] = mfma16(ah.s, fa1, acc[1]);    \
  acc[2] = mfma16(ah.s, fa2, acc[2]); acc[3] = mfma16(ah.s, fa3, acc[3]);    \
  acc[0] = mfma16(al.s, fa0, acc[0]); acc[1] = mfma16(al.s, fa1, acc[1]);    \
  acc[2] = mfma16(al.s, fa2, acc[2]); acc[3] = mfma16(al.s, fa3, acc[3]);    \
  acc[0] = mfma16(ah.s, fa4, acc[0]); acc[1] = mfma16(ah.s, fa5, acc[1]);    \
  acc[2] = mfma16(ah.s, fa6, acc[2]); acc[3] = mfma16(ah.s, fa7, acc[3]);

#define MFMAS_B()                                                            \
  acc[0] = mfma16(ah.s, fb0, acc[0]); acc[1] = mfma16(ah.s, fb1, acc[1]);    \
  acc[2] = mfma16(ah.s, fb2, acc[2]); acc[3] = mfma16(ah.s, fb3, acc[3]);    \
  acc[0] = mfma16(al.s, fb0, acc[0]); acc[1] = mfma16(al.s, fb1, acc[1]);    \
  acc[2] = mfma16(al.s, fb2, acc[2]); acc[3] = mfma16(al.s, fb3, acc[3]);    \
  acc[0] = mfma16(ah.s, fb4, acc[0]); acc[1] = mfma16(ah.s, fb5, acc[1]);    \
  acc[2] = mfma16(ah.s, fb6, acc[2]); acc[3] = mfma16(ah.s, fb7, acc[3]);

// One G1 step for chunk c: prefetch the OTHER frag set for chunk c+1 (L2,
// distance 1 step); consume x pair (SPLITX) then reload it for chunk c+3
// (consume-then-reload, distance-3 HBM cover); 12 MFMA on the current set.
#define G1A(c, X0, X1, PF, PX) {                                             \
  SB; if (PF) { LOADFB((c)+1) } SB;                                          \
  SPLITX(X0, X1) SB;                                                         \
  if (PX) { LOADX(X0, X1, (c)+3) } SB;                                       \
  MFMAS_A() SB; }

#define G1B(c, X0, X1, PF, PX) {                                             \
  SB; if (PF) { LOADFA((c)+1) } SB;                                          \
  SPLITX(X0, X1) SB;                                                         \
  if (PX) { LOADX(X0, X1, (c)+3) } SB;                                       \
  MFMAS_B() SB; }

// One wave per block, 16 rows/wave, grid 4096 -> 16 blocks/CU. No barriers.
// GEMM1: frag ping-pong (A/B named sets) + depth-3 named x pipeline.
// GEMM2: SWAPPED operands -> lane holds 4 consecutive d of one row ->
// single f32x4 coalesced store (plain, via L2; NT dropped).
__global__ __launch_bounds__(64, 4) void ea_main(const float* __restrict__ x,
                                                 const unsigned short* __restrict__ MkP,
                                                 const unsigned short* __restrict__ MvP,
                                                 float* __restrict__ out) {
  __shared__ __align__(16) unsigned short Wh[16][64];
  __shared__ __align__(16) unsigned short Wl[16][64];
  const int l = threadIdx.x;          // 0..63
  const int t = l & 15;
  const int q = l >> 4;
  const int l8 = l * 8;
  const long row0 = (long)blockIdx.x * 16;

  // ---------------- GEMM1: scores ----------------
  const float* xp = x + (row0 + t) * DDIM + 8*q;
  f32x4 acc[4];
#pragma unroll
  for (int g = 0; g < 4; ++g) acc[g] = (f32x4){0.f, 0.f, 0.f, 0.f};

  f32x4 x00,x01,x10,x11,x20,x21;                 // 3 named x pairs (depth 3)
  short8 fa0,fa1,fa2,fa3,fa4,fa5,fa6,fa7;        // frag set A
  short8 fb0,fb1,fb2,fb3,fb4,fb5,fb6,fb7;        // frag set B
  union { short8 s; unsigned short u[8]; } ah, al;

  // prologue: x chunks 0..2 (HBM, longest latency) then frags chunk 0
  LOADX(x00,x01, 0) LOADX(x10,x11, 1) LOADX(x20,x21, 2)
  SB;
  LOADFA(0)
  SB;

  // chunk c: even = set A, odd = set B; x pair = c % 3
  G1A( 0, x00,x01, 1, 1)  G1B( 1, x10,x11, 1, 1)  G1A( 2, x20,x21, 1, 1)
  G1B( 3, x00,x01, 1, 1)  G1A( 4, x10,x11, 1, 1)  G1B( 5, x20,x21, 1, 1)
  G1A( 6, x00,x01, 1, 1)  G1B( 7, x10,x11, 1, 1)  G1A( 8, x20,x21, 1, 1)
  G1B( 9, x00,x01, 1, 1)  G1A(10, x10,x11, 1, 1)  G1B(11, x20,x21, 1, 1)
  G1A(12, x00,x01, 1, 1)  G1B(13, x10,x11, 1, 1)  G1A(14, x20,x21, 1, 1)
  G1B(15, x00,x01, 1, 1)  G1A(16, x10,x11, 1, 1)  G1B(17, x20,x21, 1, 0)
  G1A(18, x00,x01, 1, 0)  G1B(19, x10,x11, 0, 0)

  // ---------------- softmax (in-register) ----------------
  // lane holds S[row = 4q+j][m = 16g+t]
  float rmax[4], rsum[4];
#pragma unroll
  for (int j = 0; j < 4; ++j)
    rmax[j] = fmaxf(fmaxf(acc[0][j], acc[1][j]), fmaxf(acc[2][j], acc[3][j]));
#pragma unroll
  for (int mk = 1; mk <= 8; mk <<= 1) {
#pragma unroll
    for (int j = 0; j < 4; ++j)
      rmax[j] = fmaxf(rmax[j], __shfl_xor(rmax[j], mk, 64));
  }
#pragma unroll
  for (int g = 0; g < 4; ++g)
#pragma unroll
    for (int j = 0; j < 4; ++j)
      acc[g][j] = exp2f((acc[g][j] - rmax[j]) * 1.44269504f);
#pragma unroll
  for (int j = 0; j < 4; ++j)
    rsum[j] = (acc[0][j] + acc[1][j]) + (acc[2][j] + acc[3][j]);
#pragma unroll
  for (int mk = 1; mk <= 8; mk <<= 1) {
#pragma unroll
    for (int j = 0; j < 4; ++j)
      rsum[j] += __shfl_xor(rsum[j], mk, 64);
  }
#pragma unroll
  for (int j = 0; j < 4; ++j) rsum[j] = 1.0f / rsum[j];

  // W -> private LDS slab, XOR swizzle (proven 0-conflict)
#pragma unroll
  for (int g = 0; g < 4; ++g)
#pragma unroll
    for (int j = 0; j < 4; ++j) {
      float wt = acc[g][j] * rsum[j];
      unsigned short hi, lo;
      splitf(wt, hi, lo);
      int row = 4*q + j;
      int ms  = (16*g + t) ^ ((row & 7) << 3);
      Wh[row][ms] = hi;
      Wl[row][ms] = lo;
    }
  // same-wave cross-lane LDS handoff
  asm volatile("s_waitcnt lgkmcnt(0)" ::: "memory");
  SB;

  // hoisted W-fragments: lane holds W[row=t][k=32c+8q+j]  (loop-invariant over n)
  short8 aH0, aH1, aL0, aL1;
  {
    const int sw  = (t & 7) << 3;
    const int ms0 = (8*q) ^ sw;
    const int ms1 = (32 + 8*q) ^ sw;
    aH0 = *(const short8*)&Wh[t][ms0];
    aH1 = *(const short8*)&Wh[t][ms1];
    aL0 = *(const short8*)&Wl[t][ms0];
    aL1 = *(const short8*)&Wl[t][ms1];
  }
  SB;

  // ---------------- GEMM2 (swapped operands): out^T tile ----------------
  // mfma(A=MvFrag, B=WFrag) -> lane (t,q) holds out[row0+t][16n+4q+j], j=0..3
  // -> one coalesced f32x4 store per n.
  short8 vAh0, vAh1, vAl0, vAl1, vBh0, vBh1, vBl0, vBl1;
  {
    const unsigned short* mvp = MvP + l8;      // n = 0
    vAh0 = *(const short8*)(mvp);        vAl0 = *(const short8*)(mvp + 512);
    vAh1 = *(const short8*)(mvp + 1024); vAl1 = *(const short8*)(mvp + 1536);
  }
  float* opb = out + (row0 + t) * DDIM + 4*q;

#pragma unroll 2
  for (int n = 0; n < 40; n += 2) {
    {   // prefetch B <- n+1
      const unsigned short* mvp = MvP + (n + 1) * 2048 + l8;
      vBh0 = *(const short8*)(mvp);        vBl0 = *(const short8*)(mvp + 512);
      vBh1 = *(const short8*)(mvp + 1024); vBl1 = *(const short8*)(mvp + 1536);
    }
    {   // compute n with A
      f32x4 o = (f32x4){0.f,0.f,0.f,0.f};
      o = mfma16(vAh0, aH0, o); o = mfma16(vAh0, aL0, o); o = mfma16(vAl0, aH0, o);
      o = mfma16(vAh1, aH1, o); o = mfma16(vAh1, aL1, o); o = mfma16(vAl1, aH1, o);
      *(f32x4*)(opb + 16*n) = o;
    }
    if (n + 2 < 40) {   // prefetch A <- n+2
      const unsigned short* mvp = MvP + (n + 2) * 2048 + l8;
      vAh0 = *(const short8*)(mvp);        vAl0 = *(const short8*)(mvp + 512);
      vAh1 = *(const short8*)(mvp + 1024); vAl1 = *(const short8*)(mvp + 1536);
    }
    {   // compute n+1 with B
      f32x4 o = (f32x4){0.f,0.f,0.f,0.f};
      o = mfma16(vBh0, aH0, o); o = mfma16(vBh0, aL0, o); o = mfma16(vBl0, aH0, o);
      o = mfma16(vBh1, aH1, o); o = mfma16(vBh1, aL1, o); o = mfma16(vBl1, aH1, o);
      *(f32x4*)(opb + 16*(n + 1)) = o;
    }
  }
}

extern "C" void kernel_launch(void* const* d_in, const int* in_sizes, int n_in,
                              void* d_out, int out_size, void* d_ws, size_t ws_size,
                              hipStream_t stream) {
  const float* x  = (const float*)d_in[0];
  const float* Mk = (const float*)d_in[1];
  const float* Mv = (const float*)d_in[2];
  float* outp = (float*)d_out;
  unsigned short* ws = (unsigned short*)d_ws;

  ea_pack<<<40, 256, 0, stream>>>(Mk, Mv, ws);
  ea_main<<<4096, 64, 0, stream>>>(x, ws, ws + MVP_OFF, outp);
}

// Round 11
// 131.959 us; speedup vs baseline: 1.3928x; 1.1289x over previous
//
#include <hip/hip_runtime.h>

typedef float  f32x4  __attribute__((ext_vector_type(4)));
typedef short  short8 __attribute__((ext_vector_type(8)));
typedef __bf16 bf16x8 __attribute__((ext_vector_type(8)));

#define DEV static __device__ __forceinline__

DEV f32x4 mfma16(short8 a, short8 b, f32x4 c) {
  return __builtin_amdgcn_mfma_f32_16x16x32_bf16(
      __builtin_bit_cast(bf16x8, a), __builtin_bit_cast(bf16x8, b), c, 0, 0, 0);
}

// split f32 into bf16 hi (truncated) + bf16 lo (RNE of residual)
DEV void splitf(float f, unsigned short& hi, unsigned short& lo) {
  unsigned u = __builtin_bit_cast(unsigned, f);
  hi = (unsigned short)(u >> 16);
  float hf = __builtin_bit_cast(float, u & 0xFFFF0000u);
  float r = f - hf;
  unsigned v = __builtin_bit_cast(unsigned, r);
  lo = (unsigned short)((v + 0x7FFFu + ((v >> 16) & 1u)) >> 16);
}

// RNE f32 -> bf16 (used where no lo-plane correction follows)
DEV unsigned short rne16(float f) {
  unsigned v = __builtin_bit_cast(unsigned, f);
  return (unsigned short)((v + 0x7FFFu + ((v >> 16) & 1u)) >> 16);
}

#define DDIM 640
#define KCH  20                    // 640 / 32 k-chunks for GEMM1
#define MKP_ELEMS (KCH*2*4*64*8)   // 81920 ushorts = 160KB  (hi+lo planes)
#define MVP_OFF   MKP_ELEMS        // MvP: hi-only, 40*2*64*8 = 40960 ushorts = 80KB

// Pack Mk (hi/lo fragment planes) and Mv^T (RNE hi-only) in MFMA fragment order.
// MkP: [c(20)][plane(2)][g(4)][lane(64)][j(8)] holds Mk[m=16g+(l&15)][d=32c+8*(l>>4)+j]
// MvP: [n(40)][c(2)][lane(64)][j(8)]           holds Mv[m=32c+8*(l>>4)+j][d=16n+(l&15)]
__global__ void ea_pack(const float* __restrict__ Mk, const float* __restrict__ Mv,
                        unsigned short* __restrict__ ws) {
  int tid = blockIdx.x * 256 + threadIdx.x;
  unsigned short* MkP = ws;
  unsigned short* MvP = ws + MVP_OFF;
  if (tid < 5120) {
    int c = tid >> 8;
    int g = (tid >> 6) & 3;
    int l = tid & 63;
    int t = l & 15, q = l >> 4;
    const float* src = Mk + (16*g + t) * DDIM + 32*c + 8*q;
    unsigned short* dh = MkP + (((c*2 + 0)*4 + g)*64 + l)*8;
    unsigned short* dl = MkP + (((c*2 + 1)*4 + g)*64 + l)*8;
#pragma unroll
    for (int j = 0; j < 8; ++j) splitf(src[j], dh[j], dl[j]);
  } else if (tid < 10240) {
    int s = tid - 5120;
    int n = s >> 7;
    int c = (s >> 6) & 1;
    int l = s & 63;
    int t = l & 15, q = l >> 4;
    const float* src = Mv + (32*c + 8*q) * DDIM + 16*n + t;
    unsigned short* dh = MvP + ((n*2 + c)*64 + l)*8;
#pragma unroll
    for (int j = 0; j < 8; ++j) dh[j] = rne16(src[j*DDIM]);
  }
}

// ---- GEMM1 helpers (verbatim R6 structure: named scalars, consume-then-reload,
// NO sched_barriers — let the compiler schedule; R10 proved pinning loses ~60us).
#define LOADX(X0, X1, c) { X0 = *(const f32x4*)(xp + 32*(c)); \
                           X1 = *(const f32x4*)(xp + 32*(c) + 4); }

#define LOADF(c) { const unsigned short* mkc_ = MkP + (c)*4096 + l*8;        \
  fh0 = *(const short8*)(mkc_);        fh1 = *(const short8*)(mkc_ + 512);   \
  fh2 = *(const short8*)(mkc_ + 1024); fh3 = *(const short8*)(mkc_ + 1536);  \
  fl0 = *(const short8*)(mkc_ + 2048); fl1 = *(const short8*)(mkc_ + 2560);  \
  fl2 = *(const short8*)(mkc_ + 3072); fl3 = *(const short8*)(mkc_ + 3584); }

#define SPLITX(X0, X1)                                                       \
  splitf(X0[0], ah.u[0], al.u[0]); splitf(X0[1], ah.u[1], al.u[1]);          \
  splitf(X0[2], ah.u[2], al.u[2]); splitf(X0[3], ah.u[3], al.u[3]);          \
  splitf(X1[0], ah.u[4], al.u[4]); splitf(X1[1], ah.u[5], al.u[5]);          \
  splitf(X1[2], ah.u[6], al.u[6]); splitf(X1[3], ah.u[7], al.u[7]);

#define MFMAS()                                                              \
  acc[0] = mfma16(ah.s, fh0, acc[0]); acc[1] = mfma16(ah.s, fh1, acc[1]);    \
  acc[2] = mfma16(ah.s, fh2, acc[2]); acc[3] = mfma16(ah.s, fh3, acc[3]);    \
  acc[0] = mfma16(al.s, fh0, acc[0]); acc[1] = mfma16(al.s, fh1, acc[1]);    \
  acc[2] = mfma16(al.s, fh2, acc[2]); acc[3] = mfma16(al.s, fh3, acc[3]);    \
  acc[0] = mfma16(ah.s, fl0, acc[0]); acc[1] = mfma16(ah.s, fl1, acc[1]);    \
  acc[2] = mfma16(ah.s, fl2, acc[2]); acc[3] = mfma16(ah.s, fl3, acc[3]);

// One wave per block (64 threads), 16 rows/wave, grid 4096 -> 16 blocks/CU.
// Fully independent waves, no barriers; GEMM1 -> in-register softmax ->
// private 4KB LDS slab (XOR swizzle) -> GEMM2 (Mv hi-only) -> plain stores.
__global__ __launch_bounds__(64, 4) void ea_main(const float* __restrict__ x,
                                                 const unsigned short* __restrict__ MkP,
                                                 const unsigned short* __restrict__ MvP,
                                                 float* __restrict__ out) {
  __shared__ __align__(16) unsigned short Wh[16][64];
  __shared__ __align__(16) unsigned short Wl[16][64];
  const int l = threadIdx.x;          // 0..63
  const int t = l & 15;
  const int q = l >> 4;
  const long row0 = (long)blockIdx.x * 16;

  // ---------------- GEMM1: scores ----------------
  const float* xp = x + (row0 + t) * DDIM + 8*q;
  f32x4 acc[4];
#pragma unroll
  for (int g = 0; g < 4; ++g) acc[g] = (f32x4){0.f, 0.f, 0.f, 0.f};

  f32x4 x00,x01,x10,x11,x20,x21,x30,x31;
  short8 fh0,fh1,fh2,fh3, fl0,fl1,fl2,fl3;
  union { short8 s; unsigned short u[8]; } ah, al;

  LOADX(x00,x01, 0) LOADX(x10,x11, 1) LOADX(x20,x21, 2) LOADX(x30,x31, 3)

#pragma unroll
  for (int cc = 0; cc < KCH; cc += 4) {
    const bool pf = (cc + 4 < KCH);
    LOADF(cc)     SPLITX(x00, x01) if (pf) { LOADX(x00,x01, cc+4) } MFMAS()
    LOADF(cc+1)   SPLITX(x10, x11) if (pf) { LOADX(x10,x11, cc+5) } MFMAS()
    LOADF(cc+2)   SPLITX(x20, x21) if (pf) { LOADX(x20,x21, cc+6) } MFMAS()
    LOADF(cc+3)   SPLITX(x30, x31) if (pf) { LOADX(x30,x31, cc+7) } MFMAS()
  }

  // ---------------- softmax (in-register) ----------------
  // lane holds S[row = 4q+j][m = 16g+t]
  float rmax[4], rsum[4];
#pragma unroll
  for (int j = 0; j < 4; ++j)
    rmax[j] = fmaxf(fmaxf(acc[0][j], acc[1][j]), fmaxf(acc[2][j], acc[3][j]));
#pragma unroll
  for (int mk = 1; mk <= 8; mk <<= 1) {
#pragma unroll
    for (int j = 0; j < 4; ++j)
      rmax[j] = fmaxf(rmax[j], __shfl_xor(rmax[j], mk, 64));
  }
#pragma unroll
  for (int g = 0; g < 4; ++g)
#pragma unroll
    for (int j = 0; j < 4; ++j)
      acc[g][j] = exp2f((acc[g][j] - rmax[j]) * 1.44269504f);
#pragma unroll
  for (int j = 0; j < 4; ++j)
    rsum[j] = (acc[0][j] + acc[1][j]) + (acc[2][j] + acc[3][j]);
#pragma unroll
  for (int mk = 1; mk <= 8; mk <<= 1) {
#pragma unroll
    for (int j = 0; j < 4; ++j)
      rsum[j] += __shfl_xor(rsum[j], mk, 64);
  }
#pragma unroll
  for (int j = 0; j < 4; ++j) rsum[j] = 1.0f / rsum[j];

  // W -> private LDS slab, XOR swizzle (proven 0-conflict)
#pragma unroll
  for (int g = 0; g < 4; ++g)
#pragma unroll
    for (int j = 0; j < 4; ++j) {
      float wt = acc[g][j] * rsum[j];
      unsigned short hi, lo;
      splitf(wt, hi, lo);
      int row = 4*q + j;
      int ms  = (16*g + t) ^ ((row & 7) << 3);
      Wh[row][ms] = hi;
      Wl[row][ms] = lo;
    }
  // same-wave cross-lane LDS handoff: wait for all ds_writes to land
  asm volatile("s_waitcnt lgkmcnt(0)" ::: "memory");
  __builtin_amdgcn_sched_barrier(0);

  // hoisted GEMM2 W-fragments: W[row=t][k=32c+8q+j]  (loop-invariant over n)
  short8 aH0, aH1, aL0, aL1;
  {
    const int sw  = (t & 7) << 3;
    const int ms0 = (8*q) ^ sw;
    const int ms1 = (32 + 8*q) ^ sw;
    aH0 = *(const short8*)&Wh[t][ms0];
    aH1 = *(const short8*)&Wh[t][ms1];
    aL0 = *(const short8*)&Wl[t][ms0];
    aL1 = *(const short8*)&Wl[t][ms1];
  }

  // ---------------- GEMM2: out = W @ Mv (Mv hi-only), named A/B buffers ----------------
  short8 vA0, vA1, vB0, vB1;
  {
    const unsigned short* mvp = MvP + l*8;     // n = 0
    vA0 = *(const short8*)(mvp);
    vA1 = *(const short8*)(mvp + 512);
  }
  float* opb = out + (row0 + 4*q) * DDIM + t;

#pragma unroll 2
  for (int n = 0; n < 40; n += 2) {
    {   // prefetch B <- n+1
      const unsigned short* mvp = MvP + (n + 1) * 1024 + l*8;
      vB0 = *(const short8*)(mvp);
      vB1 = *(const short8*)(mvp + 512);
    }
    {   // compute n with A  (4 MFMA: (Wh+Wl) x Mv_hi over both k-halves)
      f32x4 o = (f32x4){0.f,0.f,0.f,0.f};
      o = mfma16(aH0, vA0, o); o = mfma16(aL0, vA0, o);
      o = mfma16(aH1, vA1, o); o = mfma16(aL1, vA1, o);
      float* op = opb + 16*n;
#pragma unroll
      for (int j = 0; j < 4; ++j) op[j * DDIM] = o[j];
    }
    if (n + 2 < 40) {   // prefetch A <- n+2
      const unsigned short* mvp = MvP + (n + 2) * 1024 + l*8;
      vA0 = *(const short8*)(mvp);
      vA1 = *(const short8*)(mvp + 512);
    }
    {   // compute n+1 with B
      f32x4 o = (f32x4){0.f,0.f,0.f,0.f};
      o = mfma16(aH0, vB0, o); o = mfma16(aL0, vB0, o);
      o = mfma16(aH1, vB1, o); o = mfma16(aL1, vB1, o);
      float* op = opb + 16*(n + 1);
#pragma unroll
      for (int j = 0; j < 4; ++j) op[j * DDIM] = o[j];
    }
  }
}

extern "C" void kernel_launch(void* const* d_in, const int* in_sizes, int n_in,
                              void* d_out, int out_size, void* d_ws, size_t ws_size,
                              hipStream_t stream) {
  const float* x  = (const float*)d_in[0];
  const float* Mk = (const float*)d_in[1];
  const float* Mv = (const float*)d_in[2];
  float* outp = (float*)d_out;
  unsigned short* ws = (unsigned short*)d_ws;

  ea_pack<<<40, 256, 0, stream>>>(Mk, Mv, ws);
  ea_main<<<4096, 64, 0, stream>>>(x, ws, ws + MVP_OFF, outp);
}

// Round 12
// 85.251 us; speedup vs baseline: 2.1559x; 1.5479x over previous
//
#include <hip/hip_runtime.h>

typedef float  f32x4  __attribute__((ext_vector_type(4)));
typedef short  short8 __attribute__((ext_vector_type(8)));
typedef __bf16 bf16x8 __attribute__((ext_vector_type(8)));

#define DEV static __device__ __forceinline__

DEV f32x4 mfma16(short8 a, short8 b, f32x4 c) {
  return __builtin_amdgcn_mfma_f32_16x16x32_bf16(
      __builtin_bit_cast(bf16x8, a), __builtin_bit_cast(bf16x8, b), c, 0, 0, 0);
}

// split f32 into bf16 hi (truncated) + bf16 lo (RNE of residual)
DEV void splitf(float f, unsigned short& hi, unsigned short& lo) {
  unsigned u = __builtin_bit_cast(unsigned, f);
  hi = (unsigned short)(u >> 16);
  float hf = __builtin_bit_cast(float, u & 0xFFFF0000u);
  float r = f - hf;
  unsigned v = __builtin_bit_cast(unsigned, r);
  lo = (unsigned short)((v + 0x7FFFu + ((v >> 16) & 1u)) >> 16);
}

// RNE f32 -> bf16 (used where no lo-plane correction follows)
DEV unsigned short rne16(float f) {
  unsigned v = __builtin_bit_cast(unsigned, f);
  return (unsigned short)((v + 0x7FFFu + ((v >> 16) & 1u)) >> 16);
}

#define DDIM 640
#define KCH  20                    // 640 / 32 k-chunks for GEMM1
#define MKP_ELEMS (KCH*2*4*64*8)   // 81920 ushorts = 160KB  (hi+lo planes)
#define MVP_OFF   MKP_ELEMS        // MvP: hi-only, 40*2*64*8 = 40960 ushorts = 80KB

// Pack Mk (hi/lo fragment planes) and Mv^T (RNE hi-only) in MFMA fragment order.
// MkP: [c(20)][plane(2)][g(4)][lane(64)][j(8)] holds Mk[m=16g+(l&15)][d=32c+8*(l>>4)+j]
// MvP: [n(40)][c(2)][lane(64)][j(8)]           holds Mv[m=32c+8*(l>>4)+j][d=16n+(l&15)]
__global__ void ea_pack(const float* __restrict__ Mk, const float* __restrict__ Mv,
                        unsigned short* __restrict__ ws) {
  int tid = blockIdx.x * 256 + threadIdx.x;
  unsigned short* MkP = ws;
  unsigned short* MvP = ws + MVP_OFF;
  if (tid < 5120) {
    int c = tid >> 8;
    int g = (tid >> 6) & 3;
    int l = tid & 63;
    int t = l & 15, q = l >> 4;
    const float* src = Mk + (16*g + t) * DDIM + 32*c + 8*q;
    unsigned short* dh = MkP + (((c*2 + 0)*4 + g)*64 + l)*8;
    unsigned short* dl = MkP + (((c*2 + 1)*4 + g)*64 + l)*8;
#pragma unroll
    for (int j = 0; j < 8; ++j) splitf(src[j], dh[j], dl[j]);
  } else if (tid < 10240) {
    int s = tid - 5120;
    int n = s >> 7;
    int c = (s >> 6) & 1;
    int l = s & 63;
    int t = l & 15, q = l >> 4;
    const float* src = Mv + (32*c + 8*q) * DDIM + 16*n + t;
    unsigned short* dh = MvP + ((n*2 + c)*64 + l)*8;
#pragma unroll
    for (int j = 0; j < 8; ++j) dh[j] = rne16(src[j*DDIM]);
  }
}

// ---- GEMM1 helpers (verbatim R6 structure: named scalars, consume-then-reload,
// no sched_barriers in the loop — compiler-scheduled).
#define LOADX(X0, X1, c) { X0 = *(const f32x4*)(xp + 32*(c)); \
                           X1 = *(const f32x4*)(xp + 32*(c) + 4); }

#define LOADF(c) { const unsigned short* mkc_ = MkP + (c)*4096 + l*8;        \
  fh0 = *(const short8*)(mkc_);        fh1 = *(const short8*)(mkc_ + 512);   \
  fh2 = *(const short8*)(mkc_ + 1024); fh3 = *(const short8*)(mkc_ + 1536);  \
  fl0 = *(const short8*)(mkc_ + 2048); fl1 = *(const short8*)(mkc_ + 2560);  \
  fl2 = *(const short8*)(mkc_ + 3072); fl3 = *(const short8*)(mkc_ + 3584); }

#define SPLITX(X0, X1)                                                       \
  splitf(X0[0], ah.u[0], al.u[0]); splitf(X0[1], ah.u[1], al.u[1]);          \
  splitf(X0[2], ah.u[2], al.u[2]); splitf(X0[3], ah.u[3], al.u[3]);          \
  splitf(X1[0], ah.u[4], al.u[4]); splitf(X1[1], ah.u[5], al.u[5]);          \
  splitf(X1[2], ah.u[6], al.u[6]); splitf(X1[3], ah.u[7], al.u[7]);

#define MFMAS()                                                              \
  acc[0] = mfma16(ah.s, fh0, acc[0]); acc[1] = mfma16(ah.s, fh1, acc[1]);    \
  acc[2] = mfma16(ah.s, fh2, acc[2]); acc[3] = mfma16(ah.s, fh3, acc[3]);    \
  acc[0] = mfma16(al.s, fh0, acc[0]); acc[1] = mfma16(al.s, fh1, acc[1]);    \
  acc[2] = mfma16(al.s, fh2, acc[2]); acc[3] = mfma16(al.s, fh3, acc[3]);    \
  acc[0] = mfma16(ah.s, fl0, acc[0]); acc[1] = mfma16(ah.s, fl1, acc[1]);    \
  acc[2] = mfma16(ah.s, fl2, acc[2]); acc[3] = mfma16(ah.s, fl3, acc[3]);

// One wave per block (64 threads), 16 rows/wave, grid 4096 -> 16 blocks/CU.
// Fully independent waves, no barriers; GEMM1 -> in-register softmax ->
// private 4KB LDS slab (XOR swizzle) -> GEMM2 (Mv hi-only) ->
// NONTEMPORAL stores (L2 bypass keeps packed fragments L2-resident).
__global__ __launch_bounds__(64, 4) void ea_main(const float* __restrict__ x,
                                                 const unsigned short* __restrict__ MkP,
                                                 const unsigned short* __restrict__ MvP,
                                                 float* __restrict__ out) {
  __shared__ __align__(16) unsigned short Wh[16][64];
  __shared__ __align__(16) unsigned short Wl[16][64];
  const int l = threadIdx.x;          // 0..63
  const int t = l & 15;
  const int q = l >> 4;
  const long row0 = (long)blockIdx.x * 16;

  // ---------------- GEMM1: scores ----------------
  const float* xp = x + (row0 + t) * DDIM + 8*q;
  f32x4 acc[4];
#pragma unroll
  for (int g = 0; g < 4; ++g) acc[g] = (f32x4){0.f, 0.f, 0.f, 0.f};

  f32x4 x00,x01,x10,x11,x20,x21,x30,x31;
  short8 fh0,fh1,fh2,fh3, fl0,fl1,fl2,fl3;
  union { short8 s; unsigned short u[8]; } ah, al;

  LOADX(x00,x01, 0) LOADX(x10,x11, 1) LOADX(x20,x21, 2) LOADX(x30,x31, 3)

#pragma unroll
  for (int cc = 0; cc < KCH; cc += 4) {
    const bool pf = (cc + 4 < KCH);
    LOADF(cc)     SPLITX(x00, x01) if (pf) { LOADX(x00,x01, cc+4) } MFMAS()
    LOADF(cc+1)   SPLITX(x10, x11) if (pf) { LOADX(x10,x11, cc+5) } MFMAS()
    LOADF(cc+2)   SPLITX(x20, x21) if (pf) { LOADX(x20,x21, cc+6) } MFMAS()
    LOADF(cc+3)   SPLITX(x30, x31) if (pf) { LOADX(x30,x31, cc+7) } MFMAS()
  }

  // ---------------- softmax (in-register) ----------------
  // lane holds S[row = 4q+j][m = 16g+t]
  float rmax[4], rsum[4];
#pragma unroll
  for (int j = 0; j < 4; ++j)
    rmax[j] = fmaxf(fmaxf(acc[0][j], acc[1][j]), fmaxf(acc[2][j], acc[3][j]));
#pragma unroll
  for (int mk = 1; mk <= 8; mk <<= 1) {
#pragma unroll
    for (int j = 0; j < 4; ++j)
      rmax[j] = fmaxf(rmax[j], __shfl_xor(rmax[j], mk, 64));
  }
#pragma unroll
  for (int g = 0; g < 4; ++g)
#pragma unroll
    for (int j = 0; j < 4; ++j)
      acc[g][j] = exp2f((acc[g][j] - rmax[j]) * 1.44269504f);
#pragma unroll
  for (int j = 0; j < 4; ++j)
    rsum[j] = (acc[0][j] + acc[1][j]) + (acc[2][j] + acc[3][j]);
#pragma unroll
  for (int mk = 1; mk <= 8; mk <<= 1) {
#pragma unroll
    for (int j = 0; j < 4; ++j)
      rsum[j] += __shfl_xor(rsum[j], mk, 64);
  }
#pragma unroll
  for (int j = 0; j < 4; ++j) rsum[j] = 1.0f / rsum[j];

  // W -> private LDS slab, XOR swizzle (proven 0-conflict)
#pragma unroll
  for (int g = 0; g < 4; ++g)
#pragma unroll
    for (int j = 0; j < 4; ++j) {
      float wt = acc[g][j] * rsum[j];
      unsigned short hi, lo;
      splitf(wt, hi, lo);
      int row = 4*q + j;
      int ms  = (16*g + t) ^ ((row & 7) << 3);
      Wh[row][ms] = hi;
      Wl[row][ms] = lo;
    }
  // same-wave cross-lane LDS handoff: wait for all ds_writes to land
  asm volatile("s_waitcnt lgkmcnt(0)" ::: "memory");
  __builtin_amdgcn_sched_barrier(0);

  // hoisted GEMM2 W-fragments: W[row=t][k=32c+8q+j]  (loop-invariant over n)
  short8 aH0, aH1, aL0, aL1;
  {
    const int sw  = (t & 7) << 3;
    const int ms0 = (8*q) ^ sw;
    const int ms1 = (32 + 8*q) ^ sw;
    aH0 = *(const short8*)&Wh[t][ms0];
    aH1 = *(const short8*)&Wh[t][ms1];
    aL0 = *(const short8*)&Wl[t][ms0];
    aL1 = *(const short8*)&Wl[t][ms1];
  }

  // ---------------- GEMM2: out = W @ Mv (Mv hi-only), named A/B buffers ----------------
  short8 vA0, vA1, vB0, vB1;
  {
    const unsigned short* mvp = MvP + l*8;     // n = 0
    vA0 = *(const short8*)(mvp);
    vA1 = *(const short8*)(mvp + 512);
  }
  float* opb = out + (row0 + 4*q) * DDIM + t;

#pragma unroll 2
  for (int n = 0; n < 40; n += 2) {
    {   // prefetch B <- n+1
      const unsigned short* mvp = MvP + (n + 1) * 1024 + l*8;
      vB0 = *(const short8*)(mvp);
      vB1 = *(const short8*)(mvp + 512);
    }
    {   // compute n with A  (4 MFMA: (Wh+Wl) x Mv_hi over both k-halves)
      f32x4 o = (f32x4){0.f,0.f,0.f,0.f};
      o = mfma16(aH0, vA0, o); o = mfma16(aL0, vA0, o);
      o = mfma16(aH1, vA1, o); o = mfma16(aL1, vA1, o);
      float* op = opb + 16*n;
#pragma unroll
      for (int j = 0; j < 4; ++j) __builtin_nontemporal_store(o[j], op + j*DDIM);
    }
    if (n + 2 < 40) {   // prefetch A <- n+2
      const unsigned short* mvp = MvP + (n + 2) * 1024 + l*8;
      vA0 = *(const short8*)(mvp);
      vA1 = *(const short8*)(mvp + 512);
    }
    {   // compute n+1 with B
      f32x4 o = (f32x4){0.f,0.f,0.f,0.f};
      o = mfma16(aH0, vB0, o); o = mfma16(aL0, vB0, o);
      o = mfma16(aH1, vB1, o); o = mfma16(aL1, vB1, o);
      float* op = opb + 16*(n + 1);
#pragma unroll
      for (int j = 0; j < 4; ++j) __builtin_nontemporal_store(o[j], op + j*DDIM);
    }
  }
}

extern "C" void kernel_launch(void* const* d_in, const int* in_sizes, int n_in,
                              void* d_out, int out_size, void* d_ws, size_t ws_size,
                              hipStream_t stream) {
  const float* x  = (const float*)d_in[0];
  const float* Mk = (const float*)d_in[1];
  const float* Mv = (const float*)d_in[2];
  float* outp = (float*)d_out;
  unsigned short* ws = (unsigned short*)d_ws;

  ea_pack<<<40, 256, 0, stream>>>(Mk, Mv, ws);
  ea_main<<<4096, 64, 0, stream>>>(x, ws, ws + MVP_OFF, outp);
}